// Round 6
// baseline (44.392 us; speedup 1.0000x reference)
//
#include <hip/hip_runtime.h>

typedef unsigned int uint32;

#define M_DIM 512
#define CHUNKS 16   // row-interleave factor for k1 partial sums
#define NW 4        // waves per block
#define ROWS3 32    // rows written per block in k3

// ---------------------------------------------------------------------------
// Dual-dtype input loader (safety net; inputs are f32 per the 248 MB npz).
// ---------------------------------------------------------------------------
__device__ __forceinline__ float ldin(const void* p, size_t idx, bool f32m) {
    if (f32m) return ((const float*)p)[idx];
    return __uint_as_float(((uint32)((const unsigned short*)p)[idx]) << 16);
}

__device__ __forceinline__ float dec_scalar(uint32 w) {
    return ((w & 0xFFFFu) == 0u) ? __uint_as_float(w)
                                 : __uint_as_float((w & 0xFFFFu) << 16);
}

__device__ __forceinline__ bool sniff_f32(const uint32* words) {
    int votes = 0;
    for (int k = 0; k < 64; ++k) {
        uint32 e = (words[k] >> 7) & 0xFFu;
        if (!(e >= 118u && e <= 130u)) votes++;
    }
    return votes > 16;
}

// ---------------------------------------------------------------------------
// k0: decode rho/tau and input dtype once; publish to s[0..2] in ws.
// ---------------------------------------------------------------------------
__global__ void k0_decode(const uint32* __restrict__ rho_p,
                          const uint32* __restrict__ tau_p,
                          const uint32* __restrict__ Lre_w,
                          float* __restrict__ s)
{
    if (threadIdx.x != 0 || blockIdx.x != 0) return;
    s[0] = dec_scalar(rho_p[0]);
    s[1] = dec_scalar(tau_p[0]);
    s[2] = sniff_f32(Lre_w) ? 1.0f : 0.0f;
}

// ---------------------------------------------------------------------------
// k1: REAL-PART partial toeplitz-adjoint sums over diagonals d = j - i.
// Output is re(T) only => only Lre, Tre are ever needed (im never compared).
// Lane l accumulates diagonals d = l + 64k (k<8) in registers across its
// rows; one LDS reduce at the end. Block (b,c) covers rows i % CHUNKS == c.
// Partials (f32, 2 MB) land transiently in d_out; k3 overwrites all of it.
// ---------------------------------------------------------------------------
__global__ __launch_bounds__(256) void k1_partial(
    const void* __restrict__ Lre, const void* __restrict__ Tre,
    const float* __restrict__ s, float* __restrict__ partial)
{
    __shared__ float lds[NW][M_DIM];   // 8 KB
    const int b = blockIdx.x, c = blockIdx.y;
    const int tid = threadIdx.x, w = tid >> 6, lane = tid & 63;
    const float rho = s[0];
    const bool f32m = (s[2] != 0.0f);

    float acc[8];
    #pragma unroll
    for (int k = 0; k < 8; ++k) acc[k] = 0.0f;

    const size_t base = (size_t)b * (M_DIM * M_DIM);
    for (int t = 0; t < M_DIM / (CHUNKS * NW); ++t) {   // 8 rows per wave
        const int i = c + CHUNKS * (w + NW * t);
        const size_t roff = base + (size_t)i * M_DIM;
        const int dmax = (M_DIM - 1) - i;
        #pragma unroll
        for (int k = 0; k < 8; ++k) {
            const int d = lane + (k << 6);
            if (d <= dmax) {
                const size_t idx = roff + (size_t)(i + d);
                acc[k] += ldin(Lre, idx, f32m) + rho * ldin(Tre, idx, f32m);
            }
        }
    }

    #pragma unroll
    for (int k = 0; k < 8; ++k) lds[w][lane + (k << 6)] = acc[k];
    __syncthreads();

    float* pout = partial + (size_t)(b * CHUNKS + c) * M_DIM;
    for (int d = tid; d < M_DIM; d += 256) {
        float sre = 0.f;
        #pragma unroll
        for (int ww = 0; ww < NW; ++ww) sre += lds[ww][d];
        pout[d] = sre;
    }
}

// ---------------------------------------------------------------------------
// k2: reduce CHUNKS partials -> u_re[b,d] = (adj_re - e1 term)/((M-d)*rho).
// ---------------------------------------------------------------------------
__global__ __launch_bounds__(256) void k2_reduce(
    const float* __restrict__ partial, const float* __restrict__ s,
    float* __restrict__ u)
{
    const int b = blockIdx.x, tid = threadIdx.x;
    const float rho = s[0], tau = s[1];
    const float* p = partial + (size_t)b * CHUNKS * M_DIM;
    for (int d = tid; d < M_DIM; d += 256) {
        float sre = 0.f;
        #pragma unroll
        for (int cc = 0; cc < CHUNKS; ++cc) sre += p[(size_t)cc * M_DIM + d];
        if (d == 0) sre -= 0.5f * tau * (float)M_DIM;
        u[(size_t)b * M_DIM + d] = sre / ((float)(M_DIM - d) * rho);
    }
}

// ---------------------------------------------------------------------------
// k3: real-part Hermitian-Toeplitz expansion -> FLOAT32 output (B,M,M):
//   out[b,i,j] = u_re[|j - i|]   (real part is symmetric; conj flips im only)
// One float4 (4 f32) per lane, 2 per row; bound-guarded against out_elems.
// ---------------------------------------------------------------------------
__global__ __launch_bounds__(256) void k3_write(
    const float* __restrict__ u, float* __restrict__ out,
    unsigned int out_elems)
{
    __shared__ float ure[M_DIM];
    const int b = blockIdx.x, c = blockIdx.y;
    const int tid = threadIdx.x;
    for (int d = tid; d < M_DIM; d += 256)
        ure[d] = u[(size_t)b * M_DIM + d];
    __syncthreads();

    const int w = tid >> 6, lane = tid & 63;
    for (int t = 0; t < ROWS3 / NW; ++t) {          // 8 rows per wave
        const int i = c * ROWS3 + w * (ROWS3 / NW) + t;
        const size_t rbase = (size_t)(b * M_DIM + i) * M_DIM;  // f32 index
        if (rbase + M_DIM > (size_t)out_elems) continue;       // safety clamp
        float4* rowp = (float4*)(out + rbase);
        #pragma unroll
        for (int k = 0; k < 2; ++k) {
            const int q = lane + (k << 6);   // float4 index in row (0..127)
            const int j0 = q << 2;
            float4 v;
            #pragma unroll
            for (int e = 0; e < 4; ++e) {
                const int dd = j0 + e - i;
                const int a = dd < 0 ? -dd : dd;
                (&v.x)[e] = ure[a];
            }
            rowp[q] = v;
        }
    }
}

// ---------------------------------------------------------------------------
// Zero-workspace fallback: one 256-thread block per batch, fully fused.
// ---------------------------------------------------------------------------
__global__ __launch_bounds__(256) void k_fused(
    const uint32* __restrict__ rho_p, const uint32* __restrict__ tau_p,
    const void* __restrict__ Lre, const void* __restrict__ Tre,
    float* __restrict__ out, unsigned int out_elems)
{
    __shared__ float lds[NW][M_DIM];   // 8 KB
    __shared__ float ure[M_DIM];       // 2 KB
    const int b = blockIdx.x, tid = threadIdx.x, w = tid >> 6, lane = tid & 63;
    const float rho  = dec_scalar(rho_p[0]);
    const float tauv = dec_scalar(tau_p[0]);
    const bool f32m  = sniff_f32((const uint32*)Lre);

    float acc[8];
    #pragma unroll
    for (int k = 0; k < 8; ++k) acc[k] = 0.0f;

    const size_t base = (size_t)b * (M_DIM * M_DIM);
    for (int t = 0; t < M_DIM / NW; ++t) {
        const int i = w + NW * t;
        const size_t roff = base + (size_t)i * M_DIM;
        const int dmax = (M_DIM - 1) - i;
        #pragma unroll
        for (int k = 0; k < 8; ++k) {
            const int d = lane + (k << 6);
            if (d <= dmax) {
                const size_t idx = roff + (size_t)(i + d);
                acc[k] += ldin(Lre, idx, f32m) + rho * ldin(Tre, idx, f32m);
            }
        }
    }
    #pragma unroll
    for (int k = 0; k < 8; ++k) lds[w][lane + (k << 6)] = acc[k];
    __syncthreads();

    for (int d = tid; d < M_DIM; d += 256) {
        float sre = 0.f;
        #pragma unroll
        for (int ww = 0; ww < NW; ++ww) sre += lds[ww][d];
        if (d == 0) sre -= 0.5f * tauv * (float)M_DIM;
        ure[d] = sre / ((float)(M_DIM - d) * rho);
    }
    __syncthreads();

    for (int t = 0; t < M_DIM / NW; ++t) {
        const int i = w + NW * t;
        const size_t rbase = (size_t)(b * M_DIM + i) * M_DIM;
        if (rbase + M_DIM > (size_t)out_elems) continue;
        float4* rowp = (float4*)(out + rbase);
        #pragma unroll
        for (int k = 0; k < 2; ++k) {
            const int q = lane + (k << 6);
            const int j0 = q << 2;
            float4 v;
            #pragma unroll
            for (int e = 0; e < 4; ++e) {
                const int dd = j0 + e - i;
                const int a = dd < 0 ? -dd : dd;
                (&v.x)[e] = ure[a];
            }
            rowp[q] = v;
        }
    }
}

extern "C" void kernel_launch(void* const* d_in, const int* in_sizes, int n_in,
                              void* d_out, int out_size, void* d_ws, size_t ws_size,
                              hipStream_t stream)
{
    const uint32* rho = (const uint32*)d_in[0];
    const uint32* tau = (const uint32*)d_in[1];
    const void* Lre = d_in[2];
    // d_in[3] = Lamda_im, d_in[5] = Theta_im: never needed (real output only)
    const void* Tre = d_in[4];
    const int B = in_sizes[2] / (M_DIM * M_DIM);   // 64
    float* out = (float*)d_out;
    const unsigned int out_elems = (unsigned int)out_size;  // f32 elements

    // ws layout: s[16] (decoded scalars + dtype flag) + u_re[B][M]  ~128 KB
    const size_t ws_need = (16 + (size_t)B * M_DIM) * sizeof(float);
    const size_t partial_bytes = (size_t)B * CHUNKS * M_DIM * sizeof(float); // 2 MB

    if (ws_size >= ws_need &&
        (size_t)out_size * sizeof(float) >= partial_bytes) {
        float* s = (float*)d_ws;
        float* u = s + 16;
        float* partial = out;   // transient 2 MB inside the 67 MB output

        k0_decode<<<1, 1, 0, stream>>>(rho, tau, (const uint32*)Lre, s);
        dim3 g1(B, CHUNKS);
        k1_partial<<<g1, 256, 0, stream>>>(Lre, Tre, s, partial);
        k2_reduce<<<B, 256, 0, stream>>>(partial, s, u);
        dim3 g3(B, M_DIM / ROWS3);
        k3_write<<<g3, 256, 0, stream>>>(u, out, out_elems);
    } else {
        k_fused<<<B, 256, 0, stream>>>(rho, tau, Lre, Tre, out, out_elems);
    }
}

// Round 7
// 32.889 us; speedup vs baseline: 1.3497x; 1.3497x over previous
//
#include <hip/hip_runtime.h>

typedef unsigned int uint32;

#define M_DIM 512
#define CHUNKS 16   // row-interleave factor for partial sums (block.y)
#define NW 4        // waves per block

// ---------------------------------------------------------------------------
// Scalar decode (f32-vs-bf16 safety net, kept from R3-R6 debugging):
// f32 1.0f has low16 == 0; a bf16 scalar sits in low 16 bits, nonzero.
// ---------------------------------------------------------------------------
__device__ __forceinline__ float dec_scalar(uint32 w) {
    return ((w & 0xFFFFu) == 0u) ? __uint_as_float(w)
                                 : __uint_as_float((w & 0xFFFFu) << 16);
}

__device__ __forceinline__ bool sniff_f32(const uint32* words) {
    // bf16 buffer: low ushort of each word is bf16 ~N(0,1) -> exponent bits
    // (7..14) in [118,130] w.p. ~0.998; f32 mantissa bits are ~uniform.
    int votes = 0;
    for (int k = 0; k < 64; ++k) {
        uint32 e = (words[k] >> 7) & 0xFFu;
        if (!(e >= 118u && e <= 130u)) votes++;
    }
    return votes > 16;
}

__device__ __forceinline__ float bf2f(unsigned short h) {
    return __uint_as_float(((uint32)h) << 16);
}

// ---------------------------------------------------------------------------
// kA: partial real toeplitz-adjoint sums over diagonals d = j - i.
//   padj[b,c,d] = sum_{i == c (mod 16), i+d < M} (Lre[b,i,i+d] + rho*Tre[...])
// f32 fast path: float4 loads from the 4-aligned row start a0 = i - (c&3).
// Since i mod 4 == c&3 is constant per block, lane l's register accumulator
// acc[k][e] maps statically to diagonal d = 4l + 256k + e - (c&3).
//   - elements with d < 0 (e < c&3 at l=k=0) are lower-triangle garbage ->
//     accumulated but never written out;
//   - diagonals d >= 512-(c&3) have no contributing row in this block ->
//     stay at the LDS zero-init.
// ---------------------------------------------------------------------------
__global__ __launch_bounds__(256) void kA_partial(
    const void* __restrict__ Lre, const void* __restrict__ Tre,
    const uint32* __restrict__ rho_p, float* __restrict__ partial)
{
    __shared__ float lds[NW][M_DIM];   // 8 KB
    const int b = blockIdx.x, c = blockIdx.y;
    const int tid = threadIdx.x, w = tid >> 6, lane = tid & 63;
    const float rho = dec_scalar(rho_p[0]);
    const bool f32m = sniff_f32((const uint32*)Lre);

    for (int idx = tid; idx < NW * M_DIM; idx += 256) (&lds[0][0])[idx] = 0.0f;
    __syncthreads();

    const size_t base = (size_t)b * (M_DIM * M_DIM);

    if (f32m) {
        const int cm = c & 3;
        float acc[2][4];
        #pragma unroll
        for (int k = 0; k < 2; ++k)
            #pragma unroll
            for (int e = 0; e < 4; ++e) acc[k][e] = 0.0f;

        for (int t = 0; t < M_DIM / (CHUNKS * NW); ++t) {   // 8 rows per wave
            const int i = c + CHUNKS * (w + NW * t);
            const int a0 = i - cm;                          // 4-aligned start
            const int nq = (M_DIM - a0) >> 2;               // valid float4s
            const float4* rowL =
                (const float4*)((const float*)Lre + base + (size_t)i * M_DIM + a0);
            const float4* rowT =
                (const float4*)((const float*)Tre + base + (size_t)i * M_DIM + a0);
            #pragma unroll
            for (int k = 0; k < 2; ++k) {
                const int q = lane + (k << 6);
                if (q < nq) {
                    const float4 L = rowL[q];
                    const float4 T = rowT[q];
                    #pragma unroll
                    for (int e = 0; e < 4; ++e)
                        acc[k][e] += (&L.x)[e] + rho * (&T.x)[e];
                }
            }
        }
        #pragma unroll
        for (int k = 0; k < 2; ++k)
            #pragma unroll
            for (int e = 0; e < 4; ++e) {
                const int d = 4 * lane + (k << 8) + e - cm;
                if (d >= 0) lds[w][d] = acc[k][e];
            }
    } else {
        // bf16 scalar fallback (element index = ushort index)
        float acc[8];
        #pragma unroll
        for (int k = 0; k < 8; ++k) acc[k] = 0.0f;
        const unsigned short* lp = (const unsigned short*)Lre;
        const unsigned short* tp = (const unsigned short*)Tre;
        for (int t = 0; t < M_DIM / (CHUNKS * NW); ++t) {
            const int i = c + CHUNKS * (w + NW * t);
            const size_t roff = base + (size_t)i * M_DIM;
            const int dmax = (M_DIM - 1) - i;
            #pragma unroll
            for (int k = 0; k < 8; ++k) {
                const int d = lane + (k << 6);
                if (d <= dmax) {
                    const size_t idx = roff + (size_t)(i + d);
                    acc[k] += bf2f(lp[idx]) + rho * bf2f(tp[idx]);
                }
            }
        }
        #pragma unroll
        for (int k = 0; k < 8; ++k) lds[w][lane + (k << 6)] = acc[k];
    }
    __syncthreads();

    float* pout = partial + (size_t)(b * CHUNKS + c) * M_DIM;
    for (int d = tid; d < M_DIM; d += 256) {
        float s = 0.f;
        #pragma unroll
        for (int ww = 0; ww < NW; ++ww) s += lds[ww][d];
        pout[d] = s;
    }
}

// ---------------------------------------------------------------------------
// kB: fused reduce + normalize + Hermitian-Toeplitz real expansion.
// Each block (b,c) redundantly reduces batch b's 16 partials (32 KB, L2-hot),
// applies the e1 term and 1/((M-d)*rho), then writes 32 rows:
//   out[b,i,j] = u_re[|j-i|]   (real part symmetric under conj)
// ---------------------------------------------------------------------------
__global__ __launch_bounds__(256) void kB_expand(
    const float* __restrict__ partial,
    const uint32* __restrict__ rho_p, const uint32* __restrict__ tau_p,
    float* __restrict__ out, unsigned int out_elems)
{
    __shared__ float ure[M_DIM];
    const int b = blockIdx.x, c = blockIdx.y;
    const int tid = threadIdx.x;
    const float rho = dec_scalar(rho_p[0]);
    const float tau = dec_scalar(tau_p[0]);

    const float* p = partial + (size_t)b * CHUNKS * M_DIM;
    for (int d = tid; d < M_DIM; d += 256) {
        float s = 0.f;
        #pragma unroll
        for (int cc = 0; cc < CHUNKS; ++cc) s += p[(size_t)cc * M_DIM + d];
        if (d == 0) s -= 0.5f * tau * (float)M_DIM;
        ure[d] = s / ((float)(M_DIM - d) * rho);
    }
    __syncthreads();

    const int w = tid >> 6, lane = tid & 63;
    for (int t = 0; t < 8; ++t) {                       // 8 rows per wave
        const int i = c * 32 + w * 8 + t;
        const size_t rbase = (size_t)(b * M_DIM + i) * M_DIM;
        if (rbase + M_DIM > (size_t)out_elems) continue; // safety clamp
        float4* rowp = (float4*)(out + rbase);
        #pragma unroll
        for (int k = 0; k < 2; ++k) {
            const int q = lane + (k << 6);
            const int j0 = q << 2;
            float4 v;
            #pragma unroll
            for (int e = 0; e < 4; ++e) {
                const int dd = j0 + e - i;
                (&v.x)[e] = ure[dd < 0 ? -dd : dd];
            }
            rowp[q] = v;
        }
    }
}

// ---------------------------------------------------------------------------
// Mid fallback pieces (ws in [128 KB, 2 MB)): partials transient in d_out,
// separate reduce to u in ws, then expand from u.
// ---------------------------------------------------------------------------
__global__ __launch_bounds__(256) void k2_reduce(
    const float* __restrict__ partial,
    const uint32* __restrict__ rho_p, const uint32* __restrict__ tau_p,
    float* __restrict__ u)
{
    const int b = blockIdx.x, tid = threadIdx.x;
    const float rho = dec_scalar(rho_p[0]);
    const float tau = dec_scalar(tau_p[0]);
    const float* p = partial + (size_t)b * CHUNKS * M_DIM;
    for (int d = tid; d < M_DIM; d += 256) {
        float s = 0.f;
        #pragma unroll
        for (int cc = 0; cc < CHUNKS; ++cc) s += p[(size_t)cc * M_DIM + d];
        if (d == 0) s -= 0.5f * tau * (float)M_DIM;
        u[(size_t)b * M_DIM + d] = s / ((float)(M_DIM - d) * rho);
    }
}

__global__ __launch_bounds__(256) void k3_write(
    const float* __restrict__ u, float* __restrict__ out,
    unsigned int out_elems)
{
    __shared__ float ure[M_DIM];
    const int b = blockIdx.x, c = blockIdx.y;
    const int tid = threadIdx.x;
    for (int d = tid; d < M_DIM; d += 256) ure[d] = u[(size_t)b * M_DIM + d];
    __syncthreads();
    const int w = tid >> 6, lane = tid & 63;
    for (int t = 0; t < 8; ++t) {
        const int i = c * 32 + w * 8 + t;
        const size_t rbase = (size_t)(b * M_DIM + i) * M_DIM;
        if (rbase + M_DIM > (size_t)out_elems) continue;
        float4* rowp = (float4*)(out + rbase);
        #pragma unroll
        for (int k = 0; k < 2; ++k) {
            const int q = lane + (k << 6);
            const int j0 = q << 2;
            float4 v;
            #pragma unroll
            for (int e = 0; e < 4; ++e) {
                const int dd = j0 + e - i;
                (&v.x)[e] = ure[dd < 0 ? -dd : dd];
            }
            rowp[q] = v;
        }
    }
}

// ---------------------------------------------------------------------------
// Zero-workspace fallback: one 256-thread block per batch, fully fused.
// ---------------------------------------------------------------------------
__global__ __launch_bounds__(256) void k_fused(
    const uint32* __restrict__ rho_p, const uint32* __restrict__ tau_p,
    const void* __restrict__ Lre, const void* __restrict__ Tre,
    float* __restrict__ out, unsigned int out_elems)
{
    __shared__ float lds[NW][M_DIM];
    __shared__ float ure[M_DIM];
    const int b = blockIdx.x, tid = threadIdx.x, w = tid >> 6, lane = tid & 63;
    const float rho = dec_scalar(rho_p[0]);
    const float tau = dec_scalar(tau_p[0]);
    const bool f32m = sniff_f32((const uint32*)Lre);

    float acc[8];
    #pragma unroll
    for (int k = 0; k < 8; ++k) acc[k] = 0.0f;
    const size_t base = (size_t)b * (M_DIM * M_DIM);
    for (int t = 0; t < M_DIM / NW; ++t) {
        const int i = w + NW * t;
        const size_t roff = base + (size_t)i * M_DIM;
        const int dmax = (M_DIM - 1) - i;
        #pragma unroll
        for (int k = 0; k < 8; ++k) {
            const int d = lane + (k << 6);
            if (d <= dmax) {
                const size_t idx = roff + (size_t)(i + d);
                const float lv = f32m ? ((const float*)Lre)[idx]
                                      : bf2f(((const unsigned short*)Lre)[idx]);
                const float tv = f32m ? ((const float*)Tre)[idx]
                                      : bf2f(((const unsigned short*)Tre)[idx]);
                acc[k] += lv + rho * tv;
            }
        }
    }
    #pragma unroll
    for (int k = 0; k < 8; ++k) lds[w][lane + (k << 6)] = acc[k];
    __syncthreads();

    for (int d = tid; d < M_DIM; d += 256) {
        float s = 0.f;
        #pragma unroll
        for (int ww = 0; ww < NW; ++ww) s += lds[ww][d];
        if (d == 0) s -= 0.5f * tau * (float)M_DIM;
        ure[d] = s / ((float)(M_DIM - d) * rho);
    }
    __syncthreads();

    for (int t = 0; t < M_DIM / NW; ++t) {
        const int i = w + NW * t;
        const size_t rbase = (size_t)(b * M_DIM + i) * M_DIM;
        if (rbase + M_DIM > (size_t)out_elems) continue;
        float4* rowp = (float4*)(out + rbase);
        #pragma unroll
        for (int k = 0; k < 2; ++k) {
            const int q = lane + (k << 6);
            const int j0 = q << 2;
            float4 v;
            #pragma unroll
            for (int e = 0; e < 4; ++e) {
                const int dd = j0 + e - i;
                (&v.x)[e] = ure[dd < 0 ? -dd : dd];
            }
            rowp[q] = v;
        }
    }
}

extern "C" void kernel_launch(void* const* d_in, const int* in_sizes, int n_in,
                              void* d_out, int out_size, void* d_ws, size_t ws_size,
                              hipStream_t stream)
{
    const uint32* rho = (const uint32*)d_in[0];
    const uint32* tau = (const uint32*)d_in[1];
    const void* Lre = d_in[2];
    // d_in[3] (Lamda_im), d_in[5] (Theta_im): never needed — output is re(T).
    const void* Tre = d_in[4];
    const int B = in_sizes[2] / (M_DIM * M_DIM);   // 64
    float* out = (float*)d_out;
    const unsigned int out_elems = (unsigned int)out_size;  // f32 elements

    const size_t partial_bytes = (size_t)B * CHUNKS * M_DIM * sizeof(float); // 2 MB
    const size_t u_bytes = (size_t)B * M_DIM * sizeof(float);                // 128 KB

    dim3 grid(B, CHUNKS);
    if (ws_size >= partial_bytes) {
        // Fast path: 2 kernels, partials in ws.
        float* partial = (float*)d_ws;
        kA_partial<<<grid, 256, 0, stream>>>(Lre, Tre, rho, partial);
        kB_expand<<<grid, 256, 0, stream>>>(partial, rho, tau, out, out_elems);
    } else if (ws_size >= u_bytes &&
               (size_t)out_size * sizeof(float) >= partial_bytes) {
        // Mid path: partials transient in d_out (sequential kernels, no race).
        float* partial = out;
        float* u = (float*)d_ws;
        kA_partial<<<grid, 256, 0, stream>>>(Lre, Tre, rho, partial);
        k2_reduce<<<B, 256, 0, stream>>>(partial, rho, tau, u);
        k3_write<<<grid, 256, 0, stream>>>(u, out, out_elems);
    } else {
        k_fused<<<B, 256, 0, stream>>>(rho, tau, Lre, Tre, out, out_elems);
    }
}